// Round 1
// baseline (1557.748 us; speedup 1.0000x reference)
//
#include <hip/hip_runtime.h>
#include <math.h>

// Problem: MPMatcher  S=6, B=16, L=8, M=256, K=128
// Phase 1 (PASSING, DO NOT TOUCH): cost f32, ocml logf, *(1/6) reciprocal mean.
// Phase 2: reference's buggy greedy walk, f64-exact. R12:
//   - dummy candidates are consumed as a prefix of a per-row (v desc, j asc)
//     sorted list (unused-dummy v frozen during a walk) -> bitonic sort of the
//     128 dummy (v,j) pairs at row start, off the serial path
//   - dummy candidate (jd, v, u-snapshot) known at ITERATION START ->
//     speculative next-row ds_read fully hides LDS latency on march steps
//   - dummy-won iterations skip ballot/extraction and u-broadcast readlanes
//   - per-dummy dual updates deferred via suffix-sum (Dcons) applied at commit
//   - real side unchanged: value-DPP ladder + ballot extraction (R9),
//     register u accumulation (R9), rows 1..128 pre-matched (R8)

#define S_ 6
#define B_ 16
#define L_ 8
#define M_ 256
#define K_ 128

// ---------------------------------------------------------------- cost kernel
__global__ void cost_kernel(const float* __restrict__ mp,   // (6,16,8,256,2)
                            const float* __restrict__ mv,   // (6,16,256,1)
                            const float* __restrict__ gt,   // (6,16,128,2)
                            const float* __restrict__ gv,   // (6,16,128,1)
                            float* __restrict__ cost)       // (16,256,128)
{
#pragma clang fp contract(off)
    const int b = blockIdx.x;
    const int m = blockIdx.y;
    const int k = threadIdx.x;

    float accS = 0.0f;
    for (int s = 0; s < S_; ++s) {
        const int sb = s * B_ + b;
        const float gx = gt[(sb * K_ + k) * 2 + 0];
        const float gy = gt[(sb * K_ + k) * 2 + 1];
        float accL = 0.0f;
#pragma unroll
        for (int l = 0; l < L_; ++l) {
            const int base = ((sb * L_ + l) * M_ + m) * 2;
            const float dx = fabsf(mp[base + 0] - gx);
            const float dy = fabsf(mp[base + 1] - gy);
            const float diff = dx + dy;
            const float dl = (float)(L_ - (l + 1)) * 0.05f;
            const float t = diff - dl;
            accL += fmaxf(t, 0.0f);
        }
        const float meanL = accL * 0.125f;
        const float mvv = mv[sb * M_ + m];
        const float gtv = gv[sb * K_ + k];
        const float lp = -logf(mvv);
        const float ln = -logf(1.0f - mvv);
        const float val = (gtv != 0.0f) ? (5.0f * meanL + lp) : ln;
        accS += val;
    }
    cost[(b * M_ + m) * K_ + k] = accS * (1.0f / 6.0f);
}

// --------------------------------------------------------------- bit helpers
__device__ __forceinline__ double bits2d(int lo, int hi) {
    const unsigned long long u =
        ((unsigned long long)(unsigned)hi << 32) | (unsigned)lo;
    return __longlong_as_double((long long)u);
}
__device__ __forceinline__ void d2bits(double d, int& lo, int& hi) {
    const unsigned long long u = (unsigned long long)__double_as_longlong(d);
    lo = (int)(u & 0xffffffffull);
    hi = (int)(u >> 32);
}
// ascending-sortable key for DESCENDING v (ties broken by j separately).
// canonicalizes -0 -> +0 so bitwise-equal-valued v's compare equal.
__device__ __forceinline__ unsigned long long vkey_desc(double v) {
    const double c = v + 0.0;
    const unsigned long long bts = (unsigned long long)__double_as_longlong(c);
    const unsigned long long mask =
        (unsigned long long)((long long)bts >> 63) | 0x8000000000000000ull;
    return ~(bts ^ mask);
}

// ------------------------------------------------------------- matcher kernel
// One wave per batch. Lane owns real cols j=2*lane+1, 2*lane+2 (slots 0,1).
// Dummy cols j=129..256 are handled via the sorted prefix structure.
__global__ __launch_bounds__(64, 1) void match_kernel(const float* __restrict__ cost,
                                                      int* __restrict__ out)
{
#pragma clang fp contract(off)
    const int b = blockIdx.x;
    const int lane = threadIdx.x;   // 0..63
    const float* C = cost + (size_t)b * M_ * K_;
    const double INF = __builtin_inf();
    const int BIG = 0x7fffffff;

    __shared__ float   C_lds[M_ * K_];  // 128 KB cost slab (row-major, = global)
    __shared__ double  u_lds[257];      // u[0..256], 1-based rows
    __shared__ int     p_lds[257];      // p[j] = row matched to col j; 0 = free
    __shared__ double  vd_lds[128];     // v of dummy cols 129..256
    __shared__ double2 vurec[130];      // sorted records: (v, u[j-128] snapshot)
    __shared__ int     jrec[130];       // sorted records: dummy col index j
    __shared__ double  Dcons[128];      // usum at consumption of sorted slot t

    // stage the batch's cost slab into LDS (coalesced float4 copies)
    for (int t = lane; t < (M_ * K_) / 4; t += 64)
        ((float4*)C_lds)[t] = ((const float4*)C)[t];

    // rows 1..128 pre-matched to dummy cols 129..256 (exact, proven R8)
    for (int t = lane; t < 257; t += 64) {
        u_lds[t] = 0.0;
        p_lds[t] = (t >= 129) ? (t - 128) : 0;
    }
    for (int t = lane; t < 128; t += 64) vd_lds[t] = 0.0;
    __syncthreads();

    double v0 = 0.0, v1 = 0.0;   // real column potentials (persist across rows)

    for (int i = 129; i <= 256; ++i) {
        // ---- row start: snapshots (p static during walk; u[p[j]] of cols not
        // yet used never updated mid-walk -> snapshots valid, proven R11)
        const int pj0 = p_lds[2 * lane + 1];
        const int pj1 = p_lds[2 * lane + 2];
        float2 cc = *(const float2*)(C_lds + (i - 1) * K_ + 2 * lane);  // row i
        const double up0 = u_lds[pj0], up1 = u_lds[pj1];
        double ur0 = up0, ur1 = up1;

        // ---- bitonic sort of 128 dummies by (v desc, j asc); element e lives
        // at lane e>>1, slot e&1; off the serial walk path
        unsigned long long ks0 = vkey_desc(vd_lds[2 * lane]);
        unsigned long long ks1 = vkey_desc(vd_lds[2 * lane + 1]);
        int js0 = 2 * lane + 129;
        int js1 = 2 * lane + 130;
        for (int k = 2; k <= 128; k <<= 1) {
            const bool asc = ((lane & (k >> 1)) == 0);   // == ((e & k) == 0)
            for (int d2 = k >> 1; d2 >= 1; d2 >>= 1) {
                if (d2 == 1) {
                    // in-lane compare-exchange between slots 0 and 1
                    const bool L = (ks0 < ks1) || (ks0 == ks1 && js0 < js1);
                    if (L != asc) {
                        const unsigned long long tk = ks0; ks0 = ks1; ks1 = tk;
                        const int tj = js0; js0 = js1; js1 = tj;
                    }
                } else {
                    const int d = d2 >> 1;               // lane distance
                    const unsigned long long pk0 = __shfl_xor(ks0, d);
                    const int pj0s = __shfl_xor(js0, d);
                    const unsigned long long pk1 = __shfl_xor(ks1, d);
                    const int pj1s = __shfl_xor(js1, d);
                    const bool lower = ((lane & d) == 0);
                    const bool L0 = (ks0 < pk0) || (ks0 == pk0 && js0 < pj0s);
                    const bool L1 = (ks1 < pk1) || (ks1 == pk1 && js1 < pj1s);
                    const bool keep0 = (lower == asc) ? L0 : !L0;
                    const bool keep1 = (lower == asc) ? L1 : !L1;
                    if (!keep0) { ks0 = pk0; js0 = pj0s; }
                    if (!keep1) { ks1 = pk1; js1 = pj1s; }
                }
            }
        }
        // publish sorted records (+ sentinel so exhausted list -> dval = +INF)
        jrec[2 * lane] = js0;
        jrec[2 * lane + 1] = js1;
        vurec[2 * lane]     = make_double2(vd_lds[js0 - 129], u_lds[js0 - 128]);
        vurec[2 * lane + 1] = make_double2(vd_lds[js1 - 129], u_lds[js1 - 128]);
        if (lane == 0) { vurec[128] = make_double2(-INF, 0.0); jrec[128] = 257; }
        __syncthreads();

        double2 vuC = vurec[0]; int jdC = jrec[0];   // current dummy candidate
        double2 vuN = vurec[1]; int jdN = jrec[1];   // next (pipelined)
        int ptr = 0;

        int used = 0;            // real-slot used bits only
        double u_i0 = 0.0;
        double usum = 0.0;
        int j1 = 0;

        for (;;) {
            // speculative next-row load: if the dummy candidate wins, the walk
            // moves to row jdC-128 -> issue its cost row NOW (latency hidden)
            const float2 ccs = *(const float2*)(C_lds + (jdC - 129) * K_ + 2 * lane);
            // dummy candidate's reduced cost, exact ref expression (0-u)-v
            const double dval = (0.0 - u_i0) - vuC.x;

            // real side: cur = (cost - u[i0]) - v (exact ref op order, f64)
            double cd0 = ((double)cc.x - u_i0) - v0;
            double cd1 = ((double)cc.y - u_i0) - v1;
            if (used & 1) cd0 = INF;
            if (used & 2) cd1 = INF;
            double bv = fmin(cd0, cd1);

            // wave value-min via DPP ladder (VALU pipe), result in lane 63
            int lo, hi; d2bits(bv, lo, hi);
#define MIN_STAGE(CTRL, RM)                                                      \
            {                                                                    \
                const int nlo = __builtin_amdgcn_update_dpp(lo, lo, CTRL, RM, 0xf, false); \
                const int nhi = __builtin_amdgcn_update_dpp(hi, hi, CTRL, RM, 0xf, false); \
                const double mv2 = fmin(bits2d(lo, hi), bits2d(nlo, nhi));       \
                d2bits(mv2, lo, hi);                                             \
            }
            MIN_STAGE(0x111, 0xf)   // row_shr:1
            MIN_STAGE(0x112, 0xf)   // row_shr:2
            MIN_STAGE(0x114, 0xf)   // row_shr:4
            MIN_STAGE(0x118, 0xf)   // row_shr:8
            MIN_STAGE(0x142, 0xa)   // row_bcast:15 -> rows 1,3
            MIN_STAGE(0x143, 0xc)   // row_bcast:31 -> rows 2,3
#undef MIN_STAGE
            const int mlo = __builtin_amdgcn_readlane(lo, 63);
            const int mhi = __builtin_amdgcn_readlane(hi, 63);
            const double rmin = bits2d(mlo, mhi);

            // ref argmin = lowest j among global-min achievers; real j < dummy j
            if (rmin <= dval) {
                // ---- real column wins
                const double delta = rmin;
                usum += delta;
                if (used & 1) { ur0 += delta; v0 -= delta; }
                if (used & 2) { ur1 += delta; v1 -= delta; }

                int jr = BIG;
                if (cd1 == delta) jr = 2 * lane + 2;
                if (cd0 == delta) jr = 2 * lane + 1;
                const unsigned long long br = __ballot(jr != BIG);
                j1 = __builtin_amdgcn_readlane(jr, (int)__builtin_ctzll(br));

                const int ol = (j1 - 1) >> 1, sl = (j1 - 1) & 1;
                const int psel = sl ? pj1 : pj0;
                const int i0n = __builtin_amdgcn_readlane(psel, ol);
                if (i0n == 0) break;    // free real column -> augment

                const double usel = sl ? up1 : up0;
                int ulo, uhi; d2bits(usel, ulo, uhi);
                const double u_n = bits2d(__builtin_amdgcn_readlane(ulo, ol),
                                          __builtin_amdgcn_readlane(uhi, ol));
                if (lane == ol) used |= (1 << sl);
                u_i0 = u_n;
                // fallback load (speculation missed; rare mid-walk real step)
                cc = *(const float2*)(C_lds + (i0n - 1) * K_ + 2 * lane);
            } else {
                // ---- dummy candidate wins (march step): everything is ready
                const double delta = dval;
                usum += delta;
                if (used & 1) { ur0 += delta; v0 -= delta; }
                if (used & 2) { ur1 += delta; v1 -= delta; }
                if (lane == 0) Dcons[ptr] = usum;   // suffix-sum bookkeeping
                u_i0 = vuC.y;        // row-start u snapshot carried in record
                cc = ccs;            // speculative load was correct
                vuC = vuN; jdC = jdN;
                ++ptr;
                vuN = vurec[ptr + 1]; jdN = jrec[ptr + 1];   // refill pipeline
            }
        }

        // ---- commit: real used slots write running u; consumed dummy slots
        // apply deferred suffix-sum updates; lane 0 augments
        __syncthreads();
        if (used & 1) u_lds[pj0] = ur0;
        if (used & 2) u_lds[pj1] = ur1;
        {
            // consumed sorted slots t < ptr: v[j] -= (usum - Dcons[t]),
            // u[j-128] += (usum - Dcons[t])  (== ref's per-iteration updates)
            const int t0i = 2 * lane, t1i = 2 * lane + 1;
            if (t0i < ptr) {
                const double amt = usum - Dcons[t0i];
                u_lds[js0 - 128] += amt;
                vd_lds[js0 - 129] -= amt;
            }
            if (t1i < ptr) {
                const double amt = usum - Dcons[t1i];
                u_lds[js1 - 128] += amt;
                vd_lds[js1 - 129] -= amt;
            }
        }
        if (lane == 0) { p_lds[j1] = i; u_lds[i] = usum; }
        __syncthreads();
    }

    // out[b][k] = p[k+1] - 1 for the K real columns
    for (int j = lane; j < K_; j += 64)
        out[b * K_ + j] = p_lds[j + 1] - 1;
}

// ------------------------------------------------------------------- launcher
extern "C" void kernel_launch(void* const* d_in, const int* in_sizes, int n_in,
                              void* d_out, int out_size, void* d_ws, size_t ws_size,
                              hipStream_t stream) {
    const float* mp = (const float*)d_in[0];   // meta_points
    const float* mv = (const float*)d_in[1];   // meta_visibles
    /* d_in[2] covisibles: unused by reference */
    const float* gt = (const float*)d_in[3];   // gtpoints
    const float* gv = (const float*)d_in[4];   // gtvisibles
    int* out = (int*)d_out;                    // int32 assignment indices
    float* cost = (float*)d_ws;                // 16*256*128 fp32 = 2 MB

    dim3 gridA(B_, M_);
    cost_kernel<<<gridA, K_, 0, stream>>>(mp, mv, gt, gv, cost);
    match_kernel<<<B_, 64, 0, stream>>>(cost, out);
}

// Round 2
// 1484.729 us; speedup vs baseline: 1.0492x; 1.0492x over previous
//
#include <hip/hip_runtime.h>
#include <math.h>

// Problem: MPMatcher  S=6, B=16, L=8, M=256, K=128
// Phase 1 (PASSING, DO NOT TOUCH): cost f32, ocml logf, *(1/6) reciprocal mean.
// Phase 2: reference's buggy greedy walk, f64-exact. R13:
//   - best-free-dummy candidate (jdC, vdC, udC) maintained wave-uniform; the
//     march step's next-row ds_read issues at ITERATION TOP (latency hidden)
//   - candidate refreshed by a speculative 6-stage fmax DPP ladder (ladder B)
//     run CONCURRENTLY with the real-side fmin ladder (independent chains
//     interleave in the VALU pipe); adopted only when the march is taken
//   - no per-row sort (R12's bitonic sort regressed: ~5-6k cy/row of
//     ds_bpermute latency on the serial path); no dummy cd/extraction work
//   - real side unchanged from R11: value-DPP ladder + ballot extraction (R9),
//     register u accumulation (R9), rows 1..128 pre-matched (R8)

#define S_ 6
#define B_ 16
#define L_ 8
#define M_ 256
#define K_ 128

// ---------------------------------------------------------------- cost kernel
__global__ void cost_kernel(const float* __restrict__ mp,   // (6,16,8,256,2)
                            const float* __restrict__ mv,   // (6,16,256,1)
                            const float* __restrict__ gt,   // (6,16,128,2)
                            const float* __restrict__ gv,   // (6,16,128,1)
                            float* __restrict__ cost)       // (16,256,128)
{
#pragma clang fp contract(off)
    const int b = blockIdx.x;
    const int m = blockIdx.y;
    const int k = threadIdx.x;

    float accS = 0.0f;
    for (int s = 0; s < S_; ++s) {
        const int sb = s * B_ + b;
        const float gx = gt[(sb * K_ + k) * 2 + 0];
        const float gy = gt[(sb * K_ + k) * 2 + 1];
        float accL = 0.0f;
#pragma unroll
        for (int l = 0; l < L_; ++l) {
            const int base = ((sb * L_ + l) * M_ + m) * 2;
            const float dx = fabsf(mp[base + 0] - gx);
            const float dy = fabsf(mp[base + 1] - gy);
            const float diff = dx + dy;
            const float dl = (float)(L_ - (l + 1)) * 0.05f;
            const float t = diff - dl;
            accL += fmaxf(t, 0.0f);
        }
        const float meanL = accL * 0.125f;
        const float mvv = mv[sb * M_ + m];
        const float gtv = gv[sb * K_ + k];
        const float lp = -logf(mvv);
        const float ln = -logf(1.0f - mvv);
        const float val = (gtv != 0.0f) ? (5.0f * meanL + lp) : ln;
        accS += val;
    }
    cost[(b * M_ + m) * K_ + k] = accS * (1.0f / 6.0f);
}

// --------------------------------------------------------------- bit helpers
__device__ __forceinline__ double bits2d(int lo, int hi) {
    const unsigned long long u =
        ((unsigned long long)(unsigned)hi << 32) | (unsigned)lo;
    return __longlong_as_double((long long)u);
}
__device__ __forceinline__ void d2bits(double d, int& lo, int& hi) {
    const unsigned long long u = (unsigned long long)__double_as_longlong(d);
    lo = (int)(u & 0xffffffffull);
    hi = (int)(u >> 32);
}
__device__ __forceinline__ double readlane_d(double d, int l) {
    int lo, hi; d2bits(d, lo, hi);
    return bits2d(__builtin_amdgcn_readlane(lo, l),
                  __builtin_amdgcn_readlane(hi, l));
}

// one DPP reduction stage on a (lo,hi) f64 register pair with combiner FOP
#define RSTG(LOV, HIV, FOP, CTRL, RM)                                            \
    {                                                                            \
        const int nlo_ = __builtin_amdgcn_update_dpp(LOV, LOV, CTRL, RM, 0xf, false); \
        const int nhi_ = __builtin_amdgcn_update_dpp(HIV, HIV, CTRL, RM, 0xf, false); \
        const double r_ = FOP(bits2d(LOV, HIV), bits2d(nlo_, nhi_));             \
        d2bits(r_, LOV, HIV);                                                    \
    }
// full 64-lane ladder (result in lane 63)
#define RLADDER(LOV, HIV, FOP)                                                   \
    RSTG(LOV, HIV, FOP, 0x111, 0xf)  /* row_shr:1  */                            \
    RSTG(LOV, HIV, FOP, 0x112, 0xf)  /* row_shr:2  */                            \
    RSTG(LOV, HIV, FOP, 0x114, 0xf)  /* row_shr:4  */                            \
    RSTG(LOV, HIV, FOP, 0x118, 0xf)  /* row_shr:8  */                            \
    RSTG(LOV, HIV, FOP, 0x142, 0xa)  /* row_bcast:15 -> rows 1,3 */              \
    RSTG(LOV, HIV, FOP, 0x143, 0xc)  /* row_bcast:31 -> rows 2,3 */

// ------------------------------------------------------------- matcher kernel
// One wave per batch. Lane owns real cols j=2*lane+1, 2*lane+2 (slots 0,1)
// and dummy cols j=2*lane+129, 2*lane+130 (slots 2,3).
__global__ __launch_bounds__(64, 1) void match_kernel(const float* __restrict__ cost,
                                                      int* __restrict__ out)
{
#pragma clang fp contract(off)
    const int b = blockIdx.x;
    const int lane = threadIdx.x;   // 0..63
    const float* C = cost + (size_t)b * M_ * K_;
    const double INF = __builtin_inf();
    const double NINF = -__builtin_inf();
    const int BIG = 0x7fffffff;

    __shared__ float  C_lds[M_ * K_];   // 128 KB cost slab (row-major, = global)
    __shared__ double u_lds[257];       // u[0..256], 1-based rows
    __shared__ int    p_lds[257];       // p[j] = row matched to col j; 0 = free

    // stage the batch's cost slab into LDS (coalesced float4 copies)
    for (int t = lane; t < (M_ * K_) / 4; t += 64)
        ((float4*)C_lds)[t] = ((const float4*)C)[t];

    // rows 1..128 pre-matched to dummy cols 129..256 (exact, proven R8)
    for (int t = lane; t < 257; t += 64) {
        u_lds[t] = 0.0;
        p_lds[t] = (t >= 129) ? (t - 128) : 0;
    }
    __syncthreads();

    double v0 = 0.0, v1 = 0.0, v2 = 0.0, v3 = 0.0;  // column potentials
    const int jd2 = 2 * lane + 129;   // this lane's dummy cols
    const int jd3 = 2 * lane + 130;

    // wave-uniform best free dummy: col, its v, and u[p[col]] (= u[col-128]).
    // initial state: all v = 0, all u = 0 -> lowest j wins = 129.
    int jdC = 129; double vdC = 0.0, udC = 0.0;

    for (int i = 129; i <= 256; ++i) {
        // ---- row start: snapshots (p static during walk; u[p[j]] of cols not
        // yet used never updated mid-walk -> snapshots valid, proven R11)
        const int pj0 = p_lds[2 * lane + 1];
        const int pj1 = p_lds[2 * lane + 2];
        double ur0 = u_lds[pj0], ur1 = u_lds[pj1];
        double ur2 = u_lds[2 * lane + 1], ur3 = u_lds[2 * lane + 2];
        const double up0 = ur0, up1 = ur1, up2 = ur2, up3 = ur3;

        float2 cc = *(const float2*)(C_lds + (i - 1) * K_ + 2 * lane);
        double u_i0 = 0.0;
        int used = 0;
        int j1 = 0;
        double usum = 0.0;

        for (;;) {
            // speculative load of the dummy candidate's row, issued at the TOP
            // (jdC in [129,256] always); hides LDS latency on march steps
            const float2 ccs = *(const float2*)(C_lds + (jdC - 129) * K_ + 2 * lane);
            // dummy candidate's reduced cost, exact ref expression (0-u)-v
            const double dval = (0.0 - u_i0) - vdC;

            // real side: cur = (cost - u[i0]) - v (exact ref op order, f64)
            double cd0 = ((double)cc.x - u_i0) - v0;
            double cd1 = ((double)cc.y - u_i0) - v1;
            if (used & 1) cd0 = INF;
            if (used & 2) cd1 = INF;
            double bv = fmin(cd0, cd1);

            // ---- ladder A: wave min of real-side bv (VALU pipe, lane 63)
            int lo, hi; d2bits(bv, lo, hi);
            RLADDER(lo, hi, fmin)
            const int mlo = __builtin_amdgcn_readlane(lo, 63);
            const int mhi = __builtin_amdgcn_readlane(hi, 63);
            const double rmin = bits2d(mlo, mhi);

            // ---- ladder B (speculative lookahead): next best free dummy by v,
            // excluding the current candidate. Independent chain -> interleaves
            // with ladder A in the VALU pipe; result consumed only on a march.
            const double vm2 = ((used & 4) || (jd2 == jdC)) ? NINF : v2;
            const double vm3 = ((used & 8) || (jd3 == jdC)) ? NINF : v3;
            double bx = fmax(vm2, vm3);
            int xlo, xhi; d2bits(bx, xlo, xhi);
            RLADDER(xlo, xhi, fmax)
            const double vdN = bits2d(__builtin_amdgcn_readlane(xlo, 63),
                                      __builtin_amdgcn_readlane(xhi, 63));
            int jc = BIG;
            if (vm3 == vdN) jc = jd3;
            if (vm2 == vdN) jc = jd2;   // lower j wins within lane
            const unsigned long long bd = __ballot(jc != BIG);  // nonempty: the
            // fmax VALUE numerically equals some lane's vm (ties incl. all -INF)
            const int jdN = __builtin_amdgcn_readlane(jc, (int)__builtin_ctzll(bd));
            const int olN = (jdN - 129) >> 1, slN = (jdN - 129) & 1;
            const double udN = readlane_d(slN ? up3 : up2, olN);

            // ref argmin = lowest j among global-min achievers; real j < dummy
            // j, and dval = min over free dummies (subtraction is monotone)
            if (rmin <= dval) {
                // ---- real column wins
                const double delta = rmin;
                int jr = BIG;
                if (cd1 == delta) jr = 2 * lane + 2;
                if (cd0 == delta) jr = 2 * lane + 1;
                const unsigned long long br = __ballot(jr != BIG);
                j1 = __builtin_amdgcn_readlane(jr, (int)__builtin_ctzll(br));

                const int ol = (j1 - 1) >> 1, sl = (j1 - 1) & 1;
                const int psel = sl ? pj1 : pj0;
                const int i0n = __builtin_amdgcn_readlane(psel, ol);

                // next-row load (clamped; unused on break), then shadow work
                const int rown = (i0n > 0 ? i0n : 1) - 1;
                const float2 ccn = *(const float2*)(C_lds + rown * K_ + 2 * lane);

                // potential updates (ref order: all used cols + virtual col 0;
                // applied on the final iteration too, before break — ref-exact)
                usum += delta;
                if (used & 1) { ur0 += delta; v0 -= delta; }
                if (used & 2) { ur1 += delta; v1 -= delta; }
                if (used & 4) { ur2 += delta; v2 -= delta; }
                if (used & 8) { ur3 += delta; v3 -= delta; }

                const double u_n = readlane_d(sl ? up1 : up0, ol);

                if (i0n == 0) break;    // free real column -> augment (way==0)
                if (lane == ol) used |= (1 << sl);   // ref marks at next top
                u_i0 = u_n;
                cc = ccn;
                // dummy candidate unchanged (free dummies' v,u frozen mid-walk)
            } else {
                // ---- march step through the best dummy; fully pre-staged
                const double delta = dval;
                usum += delta;
                if (used & 1) { ur0 += delta; v0 -= delta; }
                if (used & 2) { ur1 += delta; v1 -= delta; }
                if (used & 4) { ur2 += delta; v2 -= delta; }
                if (used & 8) { ur3 += delta; v3 -= delta; }

                j1 = jdC;
                const int olc = (jdC - 129) >> 1, slc = (jdC - 129) & 1;
                if (lane == olc) used |= (4 << slc);
                u_i0 = udC;            // u[p[jdC]] row-start snapshot
                cc = ccs;              // speculative load was correct
                jdC = jdN; vdC = vdN; udC = udN;   // adopt lookahead
            }
        }

        // ---- commit: marked slots write their running u; lane 0 augments
        __syncthreads();
        if (used & 1) u_lds[pj0] = ur0;
        if (used & 2) u_lds[pj1] = ur1;
        if (used & 4) u_lds[2 * lane + 1] = ur2;   // p[jd2] = 2*lane+1
        if (used & 8) u_lds[2 * lane + 2] = ur3;   // p[jd3] = 2*lane+2
        if (lane == 0) { p_lds[j1] = i; u_lds[i] = usum; }

        // ---- next-row candidate: all dummies free again; v final, u = ur
        {
            double bx = fmax(v2, v3);
            int xlo, xhi; d2bits(bx, xlo, xhi);
            RLADDER(xlo, xhi, fmax)
            vdC = bits2d(__builtin_amdgcn_readlane(xlo, 63),
                         __builtin_amdgcn_readlane(xhi, 63));
            int jc = BIG;
            if (v3 == vdC) jc = jd3;
            if (v2 == vdC) jc = jd2;
            const unsigned long long bd = __ballot(jc != BIG);
            jdC = __builtin_amdgcn_readlane(jc, (int)__builtin_ctzll(bd));
            const int olc = (jdC - 129) >> 1, slc = (jdC - 129) & 1;
            udC = readlane_d(slc ? ur3 : ur2, olc);   // committed u value
        }
        __syncthreads();
    }

    // out[b][k] = p[k+1] - 1 for the K real columns
    for (int j = lane; j < K_; j += 64)
        out[b * K_ + j] = p_lds[j + 1] - 1;
}

// ------------------------------------------------------------------- launcher
extern "C" void kernel_launch(void* const* d_in, const int* in_sizes, int n_in,
                              void* d_out, int out_size, void* d_ws, size_t ws_size,
                              hipStream_t stream) {
    const float* mp = (const float*)d_in[0];   // meta_points
    const float* mv = (const float*)d_in[1];   // meta_visibles
    /* d_in[2] covisibles: unused by reference */
    const float* gt = (const float*)d_in[3];   // gtpoints
    const float* gv = (const float*)d_in[4];   // gtvisibles
    int* out = (int*)d_out;                    // int32 assignment indices
    float* cost = (float*)d_ws;                // 16*256*128 fp32 = 2 MB

    dim3 gridA(B_, M_);
    cost_kernel<<<gridA, K_, 0, stream>>>(mp, mv, gt, gv, cost);
    match_kernel<<<B_, 64, 0, stream>>>(cost, out);
}